// Round 14
// baseline (68.330 us; speedup 1.0000x reference)
//
#include <hip/hip_runtime.h>
#include <cstdint>

typedef unsigned int u32;
typedef unsigned short u16;
typedef unsigned long long u64;
typedef __attribute__((ext_vector_type(4))) float f32x4;
typedef __attribute__((ext_vector_type(8))) short s16x8;

#define D_IN   784
#define D_H    2048
#define D_O    10
#define T_STEPS 100

static __device__ __forceinline__ u16 f2bf_rn(float f) {
  u32 u = __float_as_uint(f);
  u32 r = u + 0x7FFFu + ((u >> 16) & 1u);
  return (u16)(r >> 16);
}
static __device__ __forceinline__ float bf2f(u16 h) {
  return __uint_as_float(((u32)h) << 16);
}
// async global->LDS DMA, 16B/lane: lds dest = base + lane*16 (linear),
// global src = per-lane address. Counted by vmcnt; __syncthreads drains.
static __device__ __forceinline__ void gl_lds16(const u32* g, void* l) {
  __builtin_amdgcn_global_load_lds(
      (const __attribute__((address_space(1))) void*)g,
      (__attribute__((address_space(3))) void*)l, 16, 0, 0);
}

// Truncation-based triple-split of an f32 pair into three packed bf16-pair
// words. r = f - trunc16(f) is exact; dropped residual <= 2^-24 * |f|.
static __device__ __forceinline__ void packpair(float f0, float f1,
                                                u32& o0, u32& o1, u32& o2) {
  u32 u0 = __float_as_uint(f0), u1 = __float_as_uint(f1);
  o0 = (u0 >> 16) | (u1 & 0xFFFF0000u);
  float r0 = __fsub_rn(f0, __uint_as_float(u0 & 0xFFFF0000u));
  float r1 = __fsub_rn(f1, __uint_as_float(u1 & 0xFFFF0000u));
  u32 v0 = __float_as_uint(r0), v1 = __float_as_uint(r1);
  o1 = (v0 >> 16) | (v1 & 0xFFFF0000u);
  float s0 = __fsub_rn(r0, __uint_as_float(v0 & 0xFFFF0000u));
  float s1 = __fsub_rn(r1, __uint_as_float(v1 & 0xFFFF0000u));
  o2 = (__float_as_uint(s0) >> 16) | (__float_as_uint(s1) & 0xFFFF0000u);
}

// ---------------------------------------------------------------------------
// K0: W2 (f32) -> bf16 hi/lo MFMA B-fragments (single copy, R11 verbatim).
// ---------------------------------------------------------------------------
__global__ __launch_bounds__(256) void k_prep_w2(const float* __restrict__ W2,
                                                 u32* __restrict__ Phi,
                                                 u32* __restrict__ Plo) {
  int t = blockIdx.x * 256 + threadIdx.x;
  if (t >= 64 * 64) return;
  int kb = t >> 6, l = t & 63;
  int o = l & 15;
  int kbase = kb * 32 + ((l >> 4) << 3);
  u32 hw[4], lw[4];
#pragma unroll
  for (int p = 0; p < 4; ++p) {
    u32 hp = 0, lp = 0;
#pragma unroll
    for (int q = 0; q < 2; ++q) {
      float f = (o < D_O) ? W2[o * D_H + kbase + 2 * p + q] : 0.0f;
      u16 h = f2bf_rn(f);
      float rr = __fsub_rn(f, bf2f(h));
      u16 lo = f2bf_rn(rr);
      hp |= ((u32)h) << (16 * q);
      lp |= ((u32)lo) << (16 * q);
    }
    hw[p] = hp; lw[p] = lp;
  }
  int base = (kb * 64 + l) * 4;
#pragma unroll
  for (int p = 0; p < 4; ++p) { Phi[base + p] = hw[p]; Plo[base + p] = lw[p]; }
}

// ---------------------------------------------------------------------------
// K1: FUSED split+GEMM (R13 verbatim, passed at launch_bounds(512,2)).
// ---------------------------------------------------------------------------
__global__ __launch_bounds__(512, 2) void k_fgemm(const float* __restrict__ x,
                                                  const float* __restrict__ W1,
                                                  const float* __restrict__ b1,
                                                  float* __restrict__ cur1) {
  __shared__ uint4 As[2][3][4][64];   // 24 KB
  __shared__ uint4 Bs[2][3][4][64];   // 24 KB
  const int tid = threadIdx.x, wave = tid >> 6, lane = tid & 63;
  const int id = blockIdx.x;
  const int sub = id >> 3;                  // 0..31
  const int mb = sub >> 2;                  // 0..7   (batch-row tile)
  const int nb = (id & 7) * 4 + (sub & 3);  // 0..31  (hidden-col tile)
  const int wm = wave >> 1, wn = wave & 1;
  const int st = tid & 255;
  const int srow = st >> 2, skq = st & 3;
  const int sfrag = srow >> 4;
  const int slane = skq * 16 + (srow & 15);
  const bool isA = (tid < 256);
  const float* srcrow = isA ? (x  + (size_t)(mb * 64 + srow) * D_IN)
                            : (W1 + (size_t)(nb * 64 + srow) * D_IN);
  f32x4 acc0 = {0.f, 0.f, 0.f, 0.f}, acc1 = {0.f, 0.f, 0.f, 0.f};
  float e[8];
  {
    const int kg = skq * 8;
    float4 v0 = *(const float4*)(srcrow + kg);
    float4 v1 = *(const float4*)(srcrow + kg + 4);
    e[0] = v0.x; e[1] = v0.y; e[2] = v0.z; e[3] = v0.w;
    e[4] = v1.x; e[5] = v1.y; e[6] = v1.z; e[7] = v1.w;
  }
  {  // prologue: pack kb=0 into buffer 0
    u32 w0[4], w1[4], w2[4];
#pragma unroll
    for (int p = 0; p < 4; ++p) packpair(e[2 * p], e[2 * p + 1], w0[p], w1[p], w2[p]);
    if (isA) {
      As[0][0][sfrag][slane] = make_uint4(w0[0], w0[1], w0[2], w0[3]);
      As[0][1][sfrag][slane] = make_uint4(w1[0], w1[1], w1[2], w1[3]);
      As[0][2][sfrag][slane] = make_uint4(w2[0], w2[1], w2[2], w2[3]);
    } else {
      Bs[0][0][sfrag][slane] = make_uint4(w0[0], w0[1], w0[2], w0[3]);
      Bs[0][1][sfrag][slane] = make_uint4(w1[0], w1[1], w1[2], w1[3]);
      Bs[0][2][sfrag][slane] = make_uint4(w2[0], w2[1], w2[2], w2[3]);
    }
  }
  __syncthreads();
  for (int kb = 0; kb < 25; ++kb) {
    const int cur = kb & 1, nxt = cur ^ 1;
    if (kb < 24) {       // issue next-chunk loads early
      const int kg = (kb + 1) * 32 + skq * 8;
      if (kg < D_IN) {
        float4 v0 = *(const float4*)(srcrow + kg);
        float4 v1 = *(const float4*)(srcrow + kg + 4);
        e[0] = v0.x; e[1] = v0.y; e[2] = v0.z; e[3] = v0.w;
        e[4] = v1.x; e[5] = v1.y; e[6] = v1.z; e[7] = v1.w;
      } else {
#pragma unroll
        for (int q = 0; q < 8; ++q) e[q] = 0.0f;
      }
    }
    s16x8 A0 = __builtin_bit_cast(s16x8, As[cur][0][wm][lane]);
    s16x8 A1 = __builtin_bit_cast(s16x8, As[cur][1][wm][lane]);
    s16x8 A2 = __builtin_bit_cast(s16x8, As[cur][2][wm][lane]);
    {
      s16x8 B0 = __builtin_bit_cast(s16x8, Bs[cur][0][wn * 2][lane]);
      s16x8 B1 = __builtin_bit_cast(s16x8, Bs[cur][1][wn * 2][lane]);
      s16x8 B2 = __builtin_bit_cast(s16x8, Bs[cur][2][wn * 2][lane]);
      acc0 = __builtin_amdgcn_mfma_f32_16x16x32_bf16(A0, B0, acc0, 0, 0, 0);
      acc0 = __builtin_amdgcn_mfma_f32_16x16x32_bf16(A0, B1, acc0, 0, 0, 0);
      acc0 = __builtin_amdgcn_mfma_f32_16x16x32_bf16(A1, B0, acc0, 0, 0, 0);
      acc0 = __builtin_amdgcn_mfma_f32_16x16x32_bf16(A1, B1, acc0, 0, 0, 0);
      acc0 = __builtin_amdgcn_mfma_f32_16x16x32_bf16(A0, B2, acc0, 0, 0, 0);
      acc0 = __builtin_amdgcn_mfma_f32_16x16x32_bf16(A2, B0, acc0, 0, 0, 0);
    }
    {
      s16x8 B0 = __builtin_bit_cast(s16x8, Bs[cur][0][wn * 2 + 1][lane]);
      s16x8 B1 = __builtin_bit_cast(s16x8, Bs[cur][1][wn * 2 + 1][lane]);
      s16x8 B2 = __builtin_bit_cast(s16x8, Bs[cur][2][wn * 2 + 1][lane]);
      acc1 = __builtin_amdgcn_mfma_f32_16x16x32_bf16(A0, B0, acc1, 0, 0, 0);
      acc1 = __builtin_amdgcn_mfma_f32_16x16x32_bf16(A0, B1, acc1, 0, 0, 0);
      acc1 = __builtin_amdgcn_mfma_f32_16x16x32_bf16(A1, B0, acc1, 0, 0, 0);
      acc1 = __builtin_amdgcn_mfma_f32_16x16x32_bf16(A1, B1, acc1, 0, 0, 0);
      acc1 = __builtin_amdgcn_mfma_f32_16x16x32_bf16(A0, B2, acc1, 0, 0, 0);
      acc1 = __builtin_amdgcn_mfma_f32_16x16x32_bf16(A2, B0, acc1, 0, 0, 0);
    }
    if (kb < 24) {       // pack (waits on the early loads) + write next buf
      u32 w0[4], w1[4], w2[4];
#pragma unroll
      for (int p = 0; p < 4; ++p) packpair(e[2 * p], e[2 * p + 1], w0[p], w1[p], w2[p]);
      if (isA) {
        As[nxt][0][sfrag][slane] = make_uint4(w0[0], w0[1], w0[2], w0[3]);
        As[nxt][1][sfrag][slane] = make_uint4(w1[0], w1[1], w1[2], w1[3]);
        As[nxt][2][sfrag][slane] = make_uint4(w2[0], w2[1], w2[2], w2[3]);
      } else {
        Bs[nxt][0][sfrag][slane] = make_uint4(w0[0], w0[1], w0[2], w0[3]);
        Bs[nxt][1][sfrag][slane] = make_uint4(w1[0], w1[1], w1[2], w1[3]);
        Bs[nxt][2][sfrag][slane] = make_uint4(w2[0], w2[1], w2[2], w2[3]);
      }
    }
    __syncthreads();
  }
  const int col = lane & 15, rb = (lane >> 4) * 4;
  {
    const int gcol = nb * 64 + (wn * 2) * 16 + col;
    const float bv = b1[gcol];
#pragma unroll
    for (int r = 0; r < 4; ++r)
      cur1[(size_t)(mb * 64 + wm * 16 + rb + r) * D_H + gcol] = acc0[r] + bv;
  }
  {
    const int gcol = nb * 64 + (wn * 2 + 1) * 16 + col;
    const float bv = b1[gcol];
#pragma unroll
    for (int r = 0; r < 4; ++r)
      cur1[(size_t)(mb * 64 + wm * 16 + rb + r) * D_H + gcol] = acc1[r] + bv;
  }
}

// ---------------------------------------------------------------------------
// K2: fused temporal kernel. Branchless phase B (R11 verbatim). Phase C:
// Phi/Plo staged in double-buffered 8-kb chunks via ASYNC global_load_lds
// DMA (no VGPR round-trip -> scheduler cannot serialize the loads); chunk
// c+1's DMA is issued before computing chunk c, and the end-of-iteration
// __syncthreads() drains vmcnt -> load latency hides under 16 MFMAs+expand.
// ---------------------------------------------------------------------------
__global__ __launch_bounds__(512, 4) void k_snn6(const float* __restrict__ cur1,
                                                 const u32* __restrict__ Phi,
                                                 const u32* __restrict__ Plo,
                                                 const float* __restrict__ b2,
                                                 const float* __restrict__ beta1p,
                                                 const float* __restrict__ beta2p,
                                                 float* __restrict__ out) {
  __shared__ __align__(16) u32 bits[112][66];   // 29.6 KB
  __shared__ float c2[112][18];                 // 8 KB
  __shared__ uint4 PhiS[2][8][64];              // 16 KB (2 chunk-bufs)
  __shared__ uint4 PloS[2][8][64];              // 16 KB
  const int b = blockIdx.x;
  const int tid = threadIdx.x;
  const int wave = tid >> 6, lane = tid & 63;
  const float b1c = fminf(fmaxf(beta1p[0], 0.0f), 1.0f);
  const float b2c = fminf(fmaxf(beta2p[0], 0.0f), 1.0f);

  for (int idx = tid; idx < 12 * 66; idx += 512) bits[100 + idx / 66][idx % 66] = 0;

  // ---- phase B: branchless layer-1 recurrence (R11 verbatim) ----
  float cv[4], memv[4], spf[4];
#pragma unroll
  for (int j = 0; j < 4; ++j) {
    cv[j] = cur1[(size_t)b * D_H + j * 512 + tid];
    memv[j] = 0.0f; spf[j] = 0.0f;
  }
  for (int t = 0; t < T_STEPS; ++t) {
    u64 msk[4];
#pragma unroll
    for (int j = 0; j < 4; ++j) {
      float m = __fmul_rn(b1c, memv[j]);
      m = __fadd_rn(m, cv[j]);
      m = __fsub_rn(m, spf[j]);
      bool sp = (m > 1.0f);
      msk[j] = __ballot(sp);
      spf[j] = sp ? 1.0f : 0.0f;
      memv[j] = m;
    }
    if (lane == 0) {
      u64* rowp = (u64*)&bits[t][0];
      rowp[0 * 8 + wave] = msk[0];
      rowp[1 * 8 + wave] = msk[1];
      rowp[2 * 8 + wave] = msk[2];
      rowp[3 * 8 + wave] = msk[3];
    }
  }

  // ---- phase C: DMA-staged, double-buffered chunk pipeline ----
  {  // stage chunk 0 into buf 0 (all 8 waves; wave w owns kb-row w)
    const size_t r0 = (size_t)(0 * 8 + wave) * 64 + lane;
    gl_lds16(Phi + r0 * 4, &PhiS[0][wave][0]);
    gl_lds16(Plo + r0 * 4, &PloS[0][wave][0]);
  }
  __syncthreads();   // bits complete + chunk 0 landed (vmcnt drained)

  f32x4 acc = {0.f, 0.f, 0.f, 0.f};
  const int row0 = wave * 16 + (lane & 15);
  const int shift = (lane >> 4) * 8;
  for (int c = 0; c < 8; ++c) {
    const int p = c & 1;
    if (c < 7) {   // async issue of next chunk into the other buffer
      const size_t r0 = (size_t)((c + 1) * 8 + wave) * 64 + lane;
      gl_lds16(Phi + r0 * 4, &PhiS[p ^ 1][wave][0]);
      gl_lds16(Plo + r0 * 4, &PloS[p ^ 1][wave][0]);
    }
    __builtin_amdgcn_sched_barrier(0);   // keep DMA issue ahead of compute
    if (wave < 7) {
#pragma unroll
      for (int kk = 0; kk < 8; ++kk) {
        u32 w8 = (bits[row0][c * 8 + kk] >> shift) & 0xFFu;
        u32 u = w8 | (w8 << 15);
        uint4 a0u;
        ((u32*)&a0u)[0] = ( u        & 0x00010001u) * 0x3F80u;
        ((u32*)&a0u)[1] = ((u >> 2)  & 0x00010001u) * 0x3F80u;
        ((u32*)&a0u)[2] = ((u >> 4)  & 0x00010001u) * 0x3F80u;
        ((u32*)&a0u)[3] = ((u >> 6)  & 0x00010001u) * 0x3F80u;
        s16x8 a   = __builtin_bit_cast(s16x8, a0u);
        s16x8 bhi = __builtin_bit_cast(s16x8, PhiS[p][kk][lane]);
        s16x8 blo = __builtin_bit_cast(s16x8, PloS[p][kk][lane]);
        acc = __builtin_amdgcn_mfma_f32_16x16x32_bf16(a, bhi, acc, 0, 0, 0);
        acc = __builtin_amdgcn_mfma_f32_16x16x32_bf16(a, blo, acc, 0, 0, 0);
      }
    }
    __syncthreads();   // next chunk landed; safe to overwrite buf p next iter
  }
  if (wave < 7) {
    const int colw = lane & 15, rbase = (lane >> 4) * 4;
#pragma unroll
    for (int r = 0; r < 4; ++r) c2[wave * 16 + rbase + r][colw] = acc[r];
  }
  __syncthreads();

  // ---- phase D: layer-2 recurrence + mean + softmax (R11 verbatim) ----
  if (tid < 16) {
    const int o = tid;
    const bool valid = (o < D_O);
    const float bb = valid ? b2[o] : 0.0f;
    float m2 = 0.0f; bool s2 = false; int cnt = 0;
    for (int t0 = 0; t0 < T_STEPS; t0 += 10) {
      float cc[10];
#pragma unroll
      for (int i = 0; i < 10; ++i) cc[i] = c2[t0 + i][o];
#pragma unroll
      for (int i = 0; i < 10; ++i) {
        float cI = __fadd_rn(cc[i], bb);
        float m = __fadd_rn(__fmul_rn(b2c, m2), cI);
        if (s2) m = __fsub_rn(m, 1.0f);
        s2 = (m > 1.0f);
        m2 = m;
        cnt += s2 ? 1 : 0;
      }
    }
    float mean = valid ? ((float)cnt / 100.0f) : -1e30f;
    float mx = mean;
#pragma unroll
    for (int i = 8; i >= 1; i >>= 1) mx = fmaxf(mx, __shfl_xor(mx, i, 16));
    float e = valid ? expf(mean - mx) : 0.0f;
    float s = e;
#pragma unroll
    for (int i = 8; i >= 1; i >>= 1) s = __fadd_rn(s, __shfl_xor(s, i, 16));
    if (valid) out[(size_t)b * D_O + o] = e / s;
  }
}

// ---------------------------------------------------------------------------
extern "C" void kernel_launch(void* const* d_in, const int* in_sizes, int n_in,
                              void* d_out, int out_size, void* d_ws, size_t ws_size,
                              hipStream_t stream) {
  const float* x     = (const float*)d_in[0];
  const float* W1    = (const float*)d_in[1];
  const float* b1    = (const float*)d_in[2];
  const float* W2    = (const float*)d_in[3];
  const float* b2    = (const float*)d_in[4];
  const float* beta1 = (const float*)d_in[5];
  const float* beta2 = (const float*)d_in[6];
  float* out = (float*)d_out;

  char* ws = (char*)d_ws;
  // layout: [0, 4M) cur1 | [4M, 4M+64K) Phi | [4M+64K, 4M+128K) Plo
  float* cur1 = (float*)ws;
  u32*   Phi  = (u32*)(ws + 4194304);
  u32*   Plo  = (u32*)(ws + 4259840);

  hipLaunchKernelGGL(k_prep_w2, dim3(16), dim3(256), 0, stream, W2, Phi, Plo);
  hipLaunchKernelGGL(k_fgemm, dim3(256), dim3(512), 0, stream, x, W1, b1, cur1);
  hipLaunchKernelGGL(k_snn6, dim3(512), dim3(512), 0, stream,
                     cur1, Phi, Plo, b2, beta1, beta2, out);
}